// Round 1
// baseline (621.875 us; speedup 1.0000x reference)
//
#include <hip/hip_runtime.h>
#include <hip/hip_bf16.h>

#define NEG_INF_C (-9.0e15f)
#define NEG_SLOPE_C 0.1f

constexpr int B_ = 2, N_ = 4096, IN_ = 64, H_ = 4, D_ = 32;
constexpr int NW = N_ / 32;  // 128 mask words per row

// ---------------- Kernel A: pack adj (0.0/1.0 floats) into bitmask ----------------
__global__ void pack_adj(const float* __restrict__ adj, unsigned* __restrict__ maskbits) {
    long long idx = (long long)blockIdx.x * blockDim.x + threadIdx.x;
    float a = adj[idx];
    unsigned long long ball = __ballot(a != 0.0f);
    int lane = threadIdx.x & 63;
    if (lane == 0)       maskbits[idx >> 5] = (unsigned)(ball & 0xffffffffULL);
    else if (lane == 32) maskbits[idx >> 5] = (unsigned)(ball >> 32);
}

// ---------------- Kernel B: x -> xp -> Qt (leaky applied), Kt, Vt  [B,H,N,D] ----------------
__global__ void proj_kernel(const float* __restrict__ x, const float* __restrict__ fc_w,
                            const float* __restrict__ fc_b, const float* __restrict__ Q1,
                            const float* __restrict__ Q2, const float* __restrict__ K,
                            const float* __restrict__ V, float* __restrict__ Qt,
                            float* __restrict__ Kt, float* __restrict__ Vt) {
    int bn = blockIdx.x;          // 0..B*N-1
    int b = bn / N_, n = bn % N_;
    int t = threadIdx.x;          // 0..127 (= H*D output channels)
    __shared__ float xr[IN_];
    __shared__ float xp[H_ * D_];
    if (t < IN_) xr[t] = x[(long long)bn * IN_ + t];
    __syncthreads();
    float acc = fc_b[t];
    const float* wrow = fc_w + t * IN_;
    #pragma unroll
    for (int k = 0; k < IN_; ++k) acc += xr[k] * wrow[k];
    xp[t] = acc;
    __syncthreads();
    int h = t >> 5, e = t & 31;
    const float* xph = xp + h * D_;
    const float* q1p = Q1 + h * D_ * D_;
    const float* q2p = Q2 + h * D_ * D_;
    const float* kp  = K  + h * D_ * D_;
    const float* vp  = V  + h * D_ * D_;
    float a1 = 0.f, a2 = 0.f, ak = 0.f, av = 0.f;
    #pragma unroll
    for (int d = 0; d < D_; ++d) {
        float xv = xph[d];
        a1 += xv * q1p[d * D_ + e];
        a2 += xv * q2p[d * D_ + e];
        ak += xv * kp [d * D_ + e];
        av += xv * vp [d * D_ + e];
    }
    float q = a1 + a2;
    q = q >= 0.f ? q : NEG_SLOPE_C * q;   // Qt = leaky(Qt1+Qt2)
    long long o = ((long long)(b * H_ + h) * N_ + n) * D_ + e;
    Qt[o] = q; Kt[o] = ak; Vt[o] = av;
}

// ---------------- Kernel C: flash attention with adj-bit masking ----------------
// grid: B*H*(N/64) blocks, 256 threads. thread t: row l = t&63, wave w = t>>6.
// wave w computes scores for m = w*8..w*8+7 of each 32-chunk, and PV cols w*8..w*8+7.
__global__ __launch_bounds__(256) void flash_kernel(
    const float* __restrict__ Qt, const float* __restrict__ Kt,
    const float* __restrict__ Vt, const unsigned* __restrict__ maskbits,
    float* __restrict__ out) {
    int bid = blockIdx.x;
    int bh = bid >> 6;           // 0..7
    int tile = bid & 63;         // 0..63
    int b = bh >> 2, h = bh & 3;
    int t = threadIdx.x;
    int l = t & 63;              // query row within tile
    int w = t >> 6;              // wave id
    int n = tile * 64 + l;

    __shared__ float k_lds[32 * 32];
    __shared__ float v_lds[32 * 32];
    __shared__ float s_lds[64 * 33];   // +1 pad: conflict-free row reads

    // Q row -> 32 registers
    const float* qtp = Qt + ((long long)bh * N_ + n) * D_;
    float q[32];
    #pragma unroll
    for (int d4 = 0; d4 < 8; ++d4) {
        float4 qq = reinterpret_cast<const float4*>(qtp)[d4];
        q[d4*4+0]=qq.x; q[d4*4+1]=qq.y; q[d4*4+2]=qq.z; q[d4*4+3]=qq.w;
    }
    const unsigned* mrow = maskbits + (long long)n * NW;
    const float* kbh = Kt + (long long)bh * N_ * D_;
    const float* vbh = Vt + (long long)bh * N_ * D_;

    float m_run = -3.0e38f, l_run = 0.f;
    float acc[8];
    #pragma unroll
    for (int i = 0; i < 8; ++i) acc[i] = 0.f;

    for (int c0 = 0; c0 < N_ / 32; ++c0) {
        // stage K/V chunk (32 rows x 32 cols): 256 float4 each, fully coalesced
        reinterpret_cast<float4*>(k_lds)[t] =
            reinterpret_cast<const float4*>(kbh + (long long)c0 * 32 * D_)[t];
        reinterpret_cast<float4*>(v_lds)[t] =
            reinterpret_cast<const float4*>(vbh + (long long)c0 * 32 * D_)[t];
        __syncthreads();

        // ---- QK^T: 8 scores per thread (k reads are wave-uniform -> broadcast) ----
        unsigned mw = mrow[c0];
        #pragma unroll
        for (int j = 0; j < 8; ++j) {
            int m = w * 8 + j;
            const float4* kr = reinterpret_cast<const float4*>(k_lds + m * 32);
            float s = 0.f;
            #pragma unroll
            for (int d4 = 0; d4 < 8; ++d4) {
                float4 kk = kr[d4];
                s += q[d4*4+0]*kk.x + q[d4*4+1]*kk.y + q[d4*4+2]*kk.z + q[d4*4+3]*kk.w;
            }
            float sr = s >= 0.f ? s : NEG_SLOPE_C * s;            // leaky(QKt)
            bool valid = ((mw >> m) & 1u) && (sr != 0.f);         // adj*QKt == 0 -> masked
            s_lds[l * 33 + m] = valid ? sr : NEG_INF_C;
        }
        __syncthreads();

        // ---- online softmax stats + PV (each of the 4 row-threads redundantly) ----
        float wgt[32];
        float cmax = NEG_INF_C;
        #pragma unroll
        for (int j = 0; j < 32; ++j) {
            wgt[j] = s_lds[l * 33 + j];
            cmax = fmaxf(cmax, wgt[j]);
        }
        float new_m = fmaxf(m_run, cmax);
        float scale = __expf(m_run - new_m);
        float lsum = 0.f;
        #pragma unroll
        for (int j = 0; j < 32; ++j) {
            wgt[j] = __expf(wgt[j] - new_m);
            lsum += wgt[j];
        }
        l_run = l_run * scale + lsum;
        m_run = new_m;
        #pragma unroll
        for (int i = 0; i < 8; ++i) acc[i] *= scale;
        #pragma unroll
        for (int j = 0; j < 32; ++j) {
            const float4* vr = reinterpret_cast<const float4*>(v_lds + j * 32 + w * 8);
            float wj = wgt[j];
            float4 v0 = vr[0], v1 = vr[1];
            acc[0] += wj*v0.x; acc[1] += wj*v0.y; acc[2] += wj*v0.z; acc[3] += wj*v0.w;
            acc[4] += wj*v1.x; acc[5] += wj*v1.y; acc[6] += wj*v1.z; acc[7] += wj*v1.w;
        }
        __syncthreads();
    }

    float inv = 1.f / l_run;
    long long ob = ((long long)(b * N_ + n) * H_ + h) * D_ + w * 8;
    #pragma unroll
    for (int i = 0; i < 8; ++i) {
        float v = acc[i] * inv;
        out[ob + i] = v > 0.f ? v : 0.f;   // relu
    }
}

extern "C" void kernel_launch(void* const* d_in, const int* in_sizes, int n_in,
                              void* d_out, int out_size, void* d_ws, size_t ws_size,
                              hipStream_t stream) {
    // inputs: vt, x, adj, fc_w, fc_b, Q1, Q2, K, V (all fp32)
    const float* x    = (const float*)d_in[1];
    const float* adj  = (const float*)d_in[2];
    const float* fc_w = (const float*)d_in[3];
    const float* fc_b = (const float*)d_in[4];
    const float* Q1   = (const float*)d_in[5];
    const float* Q2   = (const float*)d_in[6];
    const float* K    = (const float*)d_in[7];
    const float* V    = (const float*)d_in[8];
    float* out = (float*)d_out;

    char* ws = (char*)d_ws;
    float*    Qt    = (float*)(ws);                              // 4 MB
    float*    Kt    = (float*)(ws + (size_t)4  * 1024 * 1024);   // 4 MB
    float*    Vt    = (float*)(ws + (size_t)8  * 1024 * 1024);   // 4 MB
    unsigned* maskb = (unsigned*)(ws + (size_t)12 * 1024 * 1024);// 2 MB

    hipLaunchKernelGGL(pack_adj, dim3(N_ * N_ / 256), dim3(256), 0, stream, adj, maskb);
    hipLaunchKernelGGL(proj_kernel, dim3(B_ * N_), dim3(128), 0, stream,
                       x, fc_w, fc_b, Q1, Q2, K, V, Qt, Kt, Vt);
    hipLaunchKernelGGL(flash_kernel, dim3(B_ * H_ * (N_ / 64)), dim3(256), 0, stream,
                       Qt, Kt, Vt, maskb, out);
}

// Round 2
// 165.455 us; speedup vs baseline: 3.7586x; 3.7586x over previous
//
#include <hip/hip_runtime.h>
#include <hip/hip_bf16.h>

#define NEG_INF_C (-9.0e15f)
#define NEG_SLOPE_C 0.1f

constexpr int B_ = 2, N_ = 4096, IN_ = 64, H_ = 4, D_ = 32;
constexpr int NW = N_ / 32;  // 128 mask words per row

typedef float f32x16 __attribute__((ext_vector_type(16)));
typedef __bf16 bf16x8 __attribute__((ext_vector_type(8)));

__device__ inline unsigned short f2bfu(float x) {           // RNE f32 -> bf16 bits
    unsigned u = __float_as_uint(x);
    return (unsigned short)((u + 0x7fffu + ((u >> 16) & 1u)) >> 16);
}
__device__ inline float bfu2f(unsigned short s) { return __uint_as_float(((unsigned)s) << 16); }
__device__ inline bf16x8 ld_bf8(const unsigned short* p) {
    uint4 r = *reinterpret_cast<const uint4*>(p);
    return __builtin_bit_cast(bf16x8, r);
}

// ---------------- Kernel A: pack adj (0.0/1.0 floats) into bitmask ----------------
__global__ void pack_adj(const float* __restrict__ adj, unsigned* __restrict__ maskbits) {
    long long idx = (long long)blockIdx.x * blockDim.x + threadIdx.x;
    float a = adj[idx];
    unsigned long long ball = __ballot(a != 0.0f);
    int lane = threadIdx.x & 63;
    if (lane == 0)       maskbits[idx >> 5] = (unsigned)(ball & 0xffffffffULL);
    else if (lane == 32) maskbits[idx >> 5] = (unsigned)(ball >> 32);
}

// ------------- Kernel B: projections -> bf16 hi/lo splits + V^T (bf16) -------------
__global__ void proj_kernel(const float* __restrict__ x, const float* __restrict__ fc_w,
                            const float* __restrict__ fc_b, const float* __restrict__ Q1,
                            const float* __restrict__ Q2, const float* __restrict__ K,
                            const float* __restrict__ V,
                            unsigned short* __restrict__ QtH, unsigned short* __restrict__ QtL,
                            unsigned short* __restrict__ KtH, unsigned short* __restrict__ KtL,
                            unsigned short* __restrict__ VtT) {
    int bn = blockIdx.x;          // 0..B*N-1
    int b = bn / N_, n = bn % N_;
    int t = threadIdx.x;          // 0..127 (= H*D output channels)
    __shared__ float xr[IN_];
    __shared__ float xp[H_ * D_];
    if (t < IN_) xr[t] = x[(long long)bn * IN_ + t];
    __syncthreads();
    float acc = fc_b[t];
    const float* wrow = fc_w + t * IN_;
    #pragma unroll
    for (int k = 0; k < IN_; ++k) acc += xr[k] * wrow[k];
    xp[t] = acc;
    __syncthreads();
    int h = t >> 5, e = t & 31;
    const float* xph = xp + h * D_;
    const float* q1p = Q1 + h * D_ * D_;
    const float* q2p = Q2 + h * D_ * D_;
    const float* kp  = K  + h * D_ * D_;
    const float* vp  = V  + h * D_ * D_;
    float a1 = 0.f, a2 = 0.f, ak = 0.f, av = 0.f;
    #pragma unroll
    for (int d = 0; d < D_; ++d) {
        float xv = xph[d];
        a1 += xv * q1p[d * D_ + e];
        a2 += xv * q2p[d * D_ + e];
        ak += xv * kp [d * D_ + e];
        av += xv * vp [d * D_ + e];
    }
    float q = a1 + a2;
    q = q >= 0.f ? q : NEG_SLOPE_C * q;   // Qt = leaky(Qt1+Qt2)
    size_t o = ((size_t)(b * H_ + h) * N_ + n) * D_ + e;
    unsigned short qh = f2bfu(q);
    QtH[o] = qh;
    QtL[o] = f2bfu(q - bfu2f(qh));
    unsigned short kh = f2bfu(ak);
    KtH[o] = kh;
    KtL[o] = f2bfu(ak - bfu2f(kh));
    VtT[((size_t)(b * H_ + h) * D_ + e) * N_ + n] = f2bfu(av);
}

// ---------------- Kernel C: MFMA flash attention, 32 queries/wave, 4-way key split ----------------
__global__ __launch_bounds__(256, 4) void flash_mfma(
    const unsigned short* __restrict__ QtH, const unsigned short* __restrict__ QtL,
    const unsigned short* __restrict__ KtH, const unsigned short* __restrict__ KtL,
    const unsigned short* __restrict__ VtT, const unsigned* __restrict__ maskb,
    float* __restrict__ out) {
    const int bid = blockIdx.x;      // 1024 blocks
    const int bh = bid >> 7;         // 0..7
    const int qg = bid & 127;        // 32-query group
    const int b = bh >> 2, h = bh & 3;
    const int t = threadIdx.x;
    const int w = t >> 6;            // key-split wave 0..3
    const int l = t & 63;
    const int lq = l & 31;           // this lane's query column
    const int hi = l >> 5;
    const int q0 = qg * 32;

    const size_t bhND = (size_t)bh * N_ * D_;
    // Q B-fragments: B[k=dim][col=q], lane holds dims dc*16 + hi*8 + 0..7
    const unsigned short* qbh = QtH + bhND + (size_t)(q0 + lq) * D_ + hi * 8;
    const unsigned short* qbl = QtL + bhND + (size_t)(q0 + lq) * D_ + hi * 8;
    const bf16x8 qh0 = ld_bf8(qbh), qh1 = ld_bf8(qbh + 16);
    const bf16x8 ql0 = ld_bf8(qbl), ql1 = ld_bf8(qbl + 16);

    f32x16 acc = {};                 // O^T: row=d, col=q (lane&31)
    float m_run = -3.0e38f, l_run = 0.f;

    const unsigned short* kh_base = KtH + bhND + hi * 8;
    const unsigned short* kl_base = KtL + bhND + hi * 8;
    const unsigned short* v_base  = VtT + ((size_t)bh * D_ + lq) * N_ + hi * 8;
    const unsigned* m_base = maskb + (size_t)(q0 + lq) * NW + w * 32;

    for (int it4 = 0; it4 < 8; ++it4) {
        const uint4 mr = *reinterpret_cast<const uint4*>(m_base + it4 * 4);
        const unsigned mws[4] = {mr.x, mr.y, mr.z, mr.w};
        #pragma unroll
        for (int j4 = 0; j4 < 4; ++j4) {
            const int key0 = w * 1024 + (it4 * 4 + j4) * 32;
            const unsigned mw = mws[j4];
            // K A-fragments: A[row=key][k=dim]
            const unsigned short* kp  = kh_base + (size_t)(key0 + lq) * D_;
            const unsigned short* klp = kl_base + (size_t)(key0 + lq) * D_;
            const bf16x8 kh0v = ld_bf8(kp),  kh1v = ld_bf8(kp + 16);
            const bf16x8 kl0v = ld_bf8(klp), kl1v = ld_bf8(klp + 16);
            f32x16 s = {};
            s = __builtin_amdgcn_mfma_f32_32x32x16_bf16(kh0v, qh0, s, 0, 0, 0);
            s = __builtin_amdgcn_mfma_f32_32x32x16_bf16(kh1v, qh1, s, 0, 0, 0);
            s = __builtin_amdgcn_mfma_f32_32x32x16_bf16(kh0v, ql0, s, 0, 0, 0);
            s = __builtin_amdgcn_mfma_f32_32x32x16_bf16(kh1v, ql1, s, 0, 0, 0);
            s = __builtin_amdgcn_mfma_f32_32x32x16_bf16(kl0v, qh0, s, 0, 0, 0);
            s = __builtin_amdgcn_mfma_f32_32x32x16_bf16(kl1v, qh1, s, 0, 0, 0);
            // leaky + adj-mask; lane holds S^T rows key=(r&3)+8*(r>>2)+4*hi, col q=lq
            float pv[16];
            float cmax = NEG_INF_C;
            #pragma unroll
            for (int r = 0; r < 16; ++r) {
                float v = s[r];
                v = (v >= 0.f) ? v : NEG_SLOPE_C * v;
                const int kli = (r & 3) + 8 * (r >> 2) + 4 * hi;
                const bool valid = ((mw >> kli) & 1u) && (v != 0.f);
                v = valid ? v : NEG_INF_C;
                pv[r] = v;
                cmax = fmaxf(cmax, v);
            }
            cmax = fmaxf(cmax, __shfl_xor(cmax, 32));
            if (!__all(cmax <= m_run)) {
                const float new_m = fmaxf(m_run, cmax);
                const float sc = __expf(m_run - new_m);
                l_run *= sc;
                #pragma unroll
                for (int r = 0; r < 16; ++r) acc[r] *= sc;
                m_run = new_m;
            }
            float lsum = 0.f;
            unsigned wds[8];
            #pragma unroll
            for (int r2 = 0; r2 < 8; ++r2) {
                const float e0 = __expf(pv[2 * r2]     - m_run);
                const float e1 = __expf(pv[2 * r2 + 1] - m_run);
                lsum += e0 + e1;
                wds[r2] = (unsigned)f2bfu(e0) | ((unsigned)f2bfu(e1) << 16);
            }
            lsum += __shfl_xor(lsum, 32);
            l_run += lsum;
            // redistribute P pairs across half-waves -> P^T B-fragments
            unsigned xw[8];
            #pragma unroll
            for (int r2 = 0; r2 < 8; ++r2) xw[r2] = __shfl_xor(wds[r2], 32);
            const uint4 b0 = hi ? make_uint4(xw[2], xw[3], wds[2], wds[3])
                                : make_uint4(wds[0], wds[1], xw[0], xw[1]);
            const uint4 b1 = hi ? make_uint4(xw[6], xw[7], wds[6], wds[7])
                                : make_uint4(wds[4], wds[5], xw[4], xw[5]);
            const bf16x8 p0 = __builtin_bit_cast(bf16x8, b0);
            const bf16x8 p1 = __builtin_bit_cast(bf16x8, b1);
            // V^T A-fragments: A[row=d=lq][k=key]
            const unsigned short* vp = v_base + key0;
            const bf16x8 v0 = ld_bf8(vp), v1 = ld_bf8(vp + 16);
            acc = __builtin_amdgcn_mfma_f32_32x32x16_bf16(v0, p0, acc, 0, 0, 0);
            acc = __builtin_amdgcn_mfma_f32_32x32x16_bf16(v1, p1, acc, 0, 0, 0);
        }
    }

    // ---- cross-wave flash merge (4 key-split partials) ----
    __shared__ float o_lds[4][32][32];
    __shared__ float m_lds[4][32];
    __shared__ float l_lds[4][32];
    if (hi == 0) { m_lds[w][lq] = m_run; l_lds[w][lq] = l_run; }
    #pragma unroll
    for (int r = 0; r < 16; ++r) {
        const int d = (r & 3) + 8 * (r >> 2) + 4 * hi;
        o_lds[w][d][lq] = acc[r];
    }
    __syncthreads();
    const float M = fmaxf(fmaxf(m_lds[0][lq], m_lds[1][lq]),
                          fmaxf(m_lds[2][lq], m_lds[3][lq]));
    float L = 0.f, fac[4];
    #pragma unroll
    for (int w2 = 0; w2 < 4; ++w2) {
        fac[w2] = __expf(m_lds[w2][lq] - M);
        L += l_lds[w2][lq] * fac[w2];
    }
    const float invL = 1.f / L;
    float ov[4];
    #pragma unroll
    for (int j = 0; j < 4; ++j) {
        const int d = 8 * w + 4 * hi + j;
        float v = 0.f;
        #pragma unroll
        for (int w2 = 0; w2 < 4; ++w2) v += o_lds[w2][d][lq] * fac[w2];
        v *= invL;
        ov[j] = fmaxf(v, 0.f);
    }
    float4 o = make_float4(ov[0], ov[1], ov[2], ov[3]);
    *reinterpret_cast<float4*>(out + ((size_t)(b * N_ + q0 + lq) * H_ + h) * D_ + 8 * w + 4 * hi) = o;
}

extern "C" void kernel_launch(void* const* d_in, const int* in_sizes, int n_in,
                              void* d_out, int out_size, void* d_ws, size_t ws_size,
                              hipStream_t stream) {
    // inputs: vt, x, adj, fc_w, fc_b, Q1, Q2, K, V (all fp32)
    const float* x    = (const float*)d_in[1];
    const float* adj  = (const float*)d_in[2];
    const float* fc_w = (const float*)d_in[3];
    const float* fc_b = (const float*)d_in[4];
    const float* Q1   = (const float*)d_in[5];
    const float* Q2   = (const float*)d_in[6];
    const float* K    = (const float*)d_in[7];
    const float* V    = (const float*)d_in[8];
    float* out = (float*)d_out;

    char* ws = (char*)d_ws;
    const size_t MB = 1024 * 1024;
    unsigned short* QtH = (unsigned short*)(ws);             // 2 MB each
    unsigned short* QtL = (unsigned short*)(ws + 2 * MB);
    unsigned short* KtH = (unsigned short*)(ws + 4 * MB);
    unsigned short* KtL = (unsigned short*)(ws + 6 * MB);
    unsigned short* VtT = (unsigned short*)(ws + 8 * MB);
    unsigned*     maskb = (unsigned*)    (ws + 10 * MB);     // 2 MB

    hipLaunchKernelGGL(pack_adj, dim3(N_ * N_ / 256), dim3(256), 0, stream, adj, maskb);
    hipLaunchKernelGGL(proj_kernel, dim3(B_ * N_), dim3(128), 0, stream,
                       x, fc_w, fc_b, Q1, Q2, K, V, QtH, QtL, KtH, KtL, VtT);
    hipLaunchKernelGGL(flash_mfma, dim3(B_ * H_ * (N_ / 32)), dim3(256), 0, stream,
                       QtH, QtL, KtH, KtL, VtT, maskb, out);
}

// Round 3
// 142.732 us; speedup vs baseline: 4.3569x; 1.1592x over previous
//
#include <hip/hip_runtime.h>
#include <hip/hip_bf16.h>

#define NEG_INF_C (-9.0e15f)
#define NEG_SLOPE_C 0.1f
#define LOG2E_C 1.4426950408889634f

constexpr int B_ = 2, N_ = 4096, IN_ = 64, H_ = 4, D_ = 32;

typedef float f32x16 __attribute__((ext_vector_type(16)));
typedef __bf16 bf16x8 __attribute__((ext_vector_type(8)));

__device__ inline unsigned short f2bfu(float x) {           // RNE f32 -> bf16 bits
    unsigned u = __float_as_uint(x);
    return (unsigned short)((u + 0x7fffu + ((u >> 16) & 1u)) >> 16);
}
__device__ inline float bfu2f(unsigned short s) { return __uint_as_float(((unsigned)s) << 16); }
__device__ inline bf16x8 ld_bf8(const unsigned short* p) {
    uint4 r = *reinterpret_cast<const uint4*>(p);
    return __builtin_bit_cast(bf16x8, r);
}

// ---------- Kernel A: adj -> transposed bitmask maskT[qg*N + m], bit q = adj[qg*32+q][m] ----------
__global__ __launch_bounds__(256) void pack_adjT(const float* __restrict__ adj,
                                                 unsigned* __restrict__ maskT) {
    const int g = blockIdx.x * 4 + (threadIdx.x >> 6);   // global wave id, 8192 total
    const int lane = threadIdx.x & 63;
    const int qg = g >> 6;            // 0..127
    const int mc = g & 63;            // 64-key chunk
    const float* ap = adj + (size_t)qg * 32 * N_ + mc * 64 + lane;
    unsigned word = 0;
    #pragma unroll
    for (int i = 0; i < 32; ++i) {
        unsigned long long ball = __ballot(ap[(size_t)i * N_] != 0.0f);
        word |= (unsigned)((ball >> lane) & 1ULL) << i;
    }
    maskT[(size_t)qg * N_ + mc * 64 + lane] = word;
}

// ------------- Kernel B: projections -> bf16 hi/lo splits + V row-major (bf16) -------------
__global__ __launch_bounds__(128) void proj_kernel(
    const float* __restrict__ x, const float* __restrict__ fc_w,
    const float* __restrict__ fc_b, const float* __restrict__ Q1,
    const float* __restrict__ Q2, const float* __restrict__ K,
    const float* __restrict__ V,
    unsigned short* __restrict__ QtH, unsigned short* __restrict__ QtL,
    unsigned short* __restrict__ KtH, unsigned short* __restrict__ KtL,
    unsigned short* __restrict__ Vt) {
    int bn = blockIdx.x;          // 0..B*N-1
    int b = bn / N_, n = bn % N_;
    int t = threadIdx.x;          // 0..127
    __shared__ float xr[IN_];
    __shared__ float xp[H_ * D_];
    if (t < IN_) xr[t] = x[(long long)bn * IN_ + t];
    __syncthreads();
    float acc = fc_b[t];
    const float* wrow = fc_w + t * IN_;
    #pragma unroll
    for (int k = 0; k < IN_; ++k) acc += xr[k] * wrow[k];
    xp[t] = acc;
    __syncthreads();
    int h = t >> 5, e = t & 31;
    const float* xph = xp + h * D_;
    const float* q1p = Q1 + h * D_ * D_;
    const float* q2p = Q2 + h * D_ * D_;
    const float* kp  = K  + h * D_ * D_;
    const float* vp  = V  + h * D_ * D_;
    float a1 = 0.f, a2 = 0.f, ak = 0.f, av = 0.f;
    #pragma unroll
    for (int d = 0; d < D_; ++d) {
        float xv = xph[d];
        a1 += xv * q1p[d * D_ + e];
        a2 += xv * q2p[d * D_ + e];
        ak += xv * kp [d * D_ + e];
        av += xv * vp [d * D_ + e];
    }
    float q = a1 + a2;
    q = q >= 0.f ? q : NEG_SLOPE_C * q;   // Qt = leaky(Qt1+Qt2)
    size_t o = ((size_t)(b * H_ + h) * N_ + n) * D_ + e;
    unsigned short qh = f2bfu(q);
    QtH[o] = qh;
    QtL[o] = f2bfu(q - bfu2f(qh));
    unsigned short kh = f2bfu(ak);
    KtH[o] = kh;
    KtL[o] = f2bfu(ak - bfu2f(kh));
    Vt[o]  = f2bfu(av);                   // row-major, coalesced
}

// ------------- Kernel B2: Vt [bh][n][d] -> VtT [bh][d][n] (LDS tile transpose) -------------
__global__ __launch_bounds__(256) void vtrans(const unsigned short* __restrict__ Vt,
                                              unsigned short* __restrict__ VtT) {
    const int bh = blockIdx.x >> 6;
    const int n0 = (blockIdx.x & 63) * 64;
    __shared__ unsigned short tile[64][34];
    const int t = threadIdx.x;
    {
        const int r = t >> 2, c = (t & 3) * 8;
        uint4 v = *reinterpret_cast<const uint4*>(Vt + ((size_t)bh * N_ + n0 + r) * D_ + c);
        *reinterpret_cast<uint4*>(&tile[r][c]) = v;
    }
    __syncthreads();
    {
        const int d = t >> 3, nc = (t & 7) * 8;
        unsigned short tmp[8];
        #pragma unroll
        for (int j = 0; j < 8; ++j) tmp[j] = tile[nc + j][d];
        *reinterpret_cast<uint4*>(VtT + ((size_t)bh * D_ + d) * N_ + n0 + nc) =
            *reinterpret_cast<uint4*>(tmp);
    }
}

// ---------------- Kernel C: MFMA flash attention, 32 queries/block, 8-way key split ----------------
__global__ __launch_bounds__(512, 6) void flash_mfma(
    const unsigned short* __restrict__ QtH, const unsigned short* __restrict__ QtL,
    const unsigned short* __restrict__ KtH, const unsigned short* __restrict__ KtL,
    const unsigned short* __restrict__ VtT, const unsigned* __restrict__ maskT,
    float* __restrict__ out) {
    const int bid = blockIdx.x;      // 1024 blocks
    const int bh = bid >> 7;         // 0..7
    const int qg = bid & 127;        // 32-query group
    const int b = bh >> 2, h = bh & 3;
    const int t = threadIdx.x;
    const int w = t >> 6;            // key-split wave 0..7
    const int wu = __builtin_amdgcn_readfirstlane(w);
    const int l = t & 63;
    const int lq = l & 31;           // this lane's query column
    const int hi = l >> 5;
    const int q0 = qg * 32;

    const size_t bhND = (size_t)bh * N_ * D_;
    // Q B-fragments: B[k=dim][col=q]
    const unsigned short* qbh = QtH + bhND + (size_t)(q0 + lq) * D_ + hi * 8;
    const unsigned short* qbl = QtL + bhND + (size_t)(q0 + lq) * D_ + hi * 8;
    const bf16x8 qh0 = ld_bf8(qbh), qh1 = ld_bf8(qbh + 16);
    const bf16x8 ql0 = ld_bf8(qbl), ql1 = ld_bf8(qbl + 16);

    f32x16 acc = {};                 // O^T: row=d, col=q
    float m_run = -3.0e38f, l_run = 0.f;
    const float negi = NEG_INF_C;

    const int kw0 = w * 512;
    const unsigned short* kh_p = KtH + bhND + (size_t)(kw0 + lq) * D_ + hi * 8;
    const unsigned short* kl_p = KtL + bhND + (size_t)(kw0 + lq) * D_ + hi * 8;
    const unsigned short* v_p  = VtT + ((size_t)bh * D_ + lq) * N_ + kw0 + hi * 8;
    const unsigned* mp = maskT + (size_t)qg * N_ + wu * 512;   // wave-uniform

    for (int tt = 0; tt < 16; ++tt) {
        // wave-uniform mask words for this 32-key tile -> SGPRs
        unsigned mwd[32];
        {
            const uint4* mq = reinterpret_cast<const uint4*>(mp + tt * 32);
            #pragma unroll
            for (int i = 0; i < 8; ++i) {
                uint4 v = mq[i];
                mwd[i*4] = v.x; mwd[i*4+1] = v.y; mwd[i*4+2] = v.z; mwd[i*4+3] = v.w;
            }
        }
        const bf16x8 kh0v = ld_bf8(kh_p), kh1v = ld_bf8(kh_p + 16);
        const bf16x8 kl0v = ld_bf8(kl_p), kl1v = ld_bf8(kl_p + 16);
        const bf16x8 v0   = ld_bf8(v_p),  v1   = ld_bf8(v_p + 16);
        kh_p += 32 * D_; kl_p += 32 * D_; v_p += 32;

        f32x16 s = {};
        s = __builtin_amdgcn_mfma_f32_32x32x16_bf16(kh0v, qh0, s, 0, 0, 0);
        s = __builtin_amdgcn_mfma_f32_32x32x16_bf16(kh1v, qh1, s, 0, 0, 0);
        s = __builtin_amdgcn_mfma_f32_32x32x16_bf16(kh0v, ql0, s, 0, 0, 0);
        s = __builtin_amdgcn_mfma_f32_32x32x16_bf16(kh1v, ql1, s, 0, 0, 0);
        s = __builtin_amdgcn_mfma_f32_32x32x16_bf16(kl0v, qh0, s, 0, 0, 0);
        s = __builtin_amdgcn_mfma_f32_32x32x16_bf16(kl1v, qh1, s, 0, 0, 0);

        // leaky (branch-free) + adj mask via SGPR-pair cndmask (1 VALU/elem)
        float pv[16];
        #pragma unroll
        for (int r = 0; r < 16; ++r) {
            const int j0 = (r & 3) + 8 * (r >> 2);
            const unsigned long long msk =
                (unsigned long long)mwd[j0] | ((unsigned long long)mwd[j0 + 4] << 32);
            const float v = s[r];
            const float lk = fmaf(0.45f, fabsf(v), 0.55f * v);
            asm("v_cndmask_b32 %0, %1, %2, %3"
                : "=v"(pv[r]) : "v"(negi), "v"(lk), "s"(msk));
        }
        // row max (compiler fuses to v_max3)
        float c0 = fmaxf(fmaxf(pv[0], pv[1]), fmaxf(pv[2], pv[3]));
        float c1 = fmaxf(fmaxf(pv[4], pv[5]), fmaxf(pv[6], pv[7]));
        float c2 = fmaxf(fmaxf(pv[8], pv[9]), fmaxf(pv[10], pv[11]));
        float c3 = fmaxf(fmaxf(pv[12], pv[13]), fmaxf(pv[14], pv[15]));
        float cmax = fmaxf(fmaxf(c0, c1), fmaxf(c2, c3));
        cmax = fmaxf(cmax, __shfl_xor(cmax, 32));
        if (!__all(cmax <= m_run)) {
            const float nm = fmaxf(m_run, cmax);
            const float sc = exp2f((m_run - nm) * LOG2E_C);
            l_run *= sc;
            #pragma unroll
            for (int r = 0; r < 16; ++r) acc[r] *= sc;
            m_run = nm;
        }
        float e[16];
        #pragma unroll
        for (int r = 0; r < 16; ++r) e[r] = exp2f((pv[r] - m_run) * LOG2E_C);
        float s0 = (e[0] + e[1]) + (e[2] + e[3]);
        float s1 = (e[4] + e[5]) + (e[6] + e[7]);
        float s2 = (e[8] + e[9]) + (e[10] + e[11]);
        float s3 = (e[12] + e[13]) + (e[14] + e[15]);
        float lsum = (s0 + s1) + (s2 + s3);
        lsum += __shfl_xor(lsum, 32);
        l_run += lsum;
        // P -> bf16 pairs (T12): 8 cvt_pk + 4 permlane32_swap
        unsigned c0w, c1w, c2w, c3w, c4w, c5w, c6w, c7w;
        asm("v_cvt_pk_bf16_f32 %0, %1, %2" : "=v"(c0w) : "v"(e[0]),  "v"(e[1]));
        asm("v_cvt_pk_bf16_f32 %0, %1, %2" : "=v"(c1w) : "v"(e[2]),  "v"(e[3]));
        asm("v_cvt_pk_bf16_f32 %0, %1, %2" : "=v"(c2w) : "v"(e[4]),  "v"(e[5]));
        asm("v_cvt_pk_bf16_f32 %0, %1, %2" : "=v"(c3w) : "v"(e[6]),  "v"(e[7]));
        asm("v_cvt_pk_bf16_f32 %0, %1, %2" : "=v"(c4w) : "v"(e[8]),  "v"(e[9]));
        asm("v_cvt_pk_bf16_f32 %0, %1, %2" : "=v"(c5w) : "v"(e[10]), "v"(e[11]));
        asm("v_cvt_pk_bf16_f32 %0, %1, %2" : "=v"(c6w) : "v"(e[12]), "v"(e[13]));
        asm("v_cvt_pk_bf16_f32 %0, %1, %2" : "=v"(c7w) : "v"(e[14]), "v"(e[15]));
        asm("v_permlane32_swap_b32 %0, %1" : "+v"(c0w), "+v"(c2w));
        asm("v_permlane32_swap_b32 %0, %1" : "+v"(c1w), "+v"(c3w));
        asm("v_permlane32_swap_b32 %0, %1" : "+v"(c4w), "+v"(c6w));
        asm("v_permlane32_swap_b32 %0, %1" : "+v"(c5w), "+v"(c7w));
        const uint4 b0u = make_uint4(c0w, c1w, c2w, c3w);
        const uint4 b1u = make_uint4(c4w, c5w, c6w, c7w);
        acc = __builtin_amdgcn_mfma_f32_32x32x16_bf16(v0, __builtin_bit_cast(bf16x8, b0u), acc, 0, 0, 0);
        acc = __builtin_amdgcn_mfma_f32_32x32x16_bf16(v1, __builtin_bit_cast(bf16x8, b1u), acc, 0, 0, 0);
    }

    // ---- cross-wave flash merge (8 key-split partials) ----
    __shared__ float o_lds[8][32][33];
    __shared__ float m_l[8][32];
    __shared__ float l_l[8][32];
    if (hi == 0) { m_l[w][lq] = m_run; l_l[w][lq] = l_run; }
    #pragma unroll
    for (int r = 0; r < 16; ++r) {
        const int d = (r & 3) + 8 * (r >> 2) + 4 * hi;
        o_lds[w][d][lq] = acc[r];
    }
    __syncthreads();
    {
        const int q = t >> 4;        // 0..31
        const int dp = t & 15;       // float2 over d
        float M = m_l[0][q];
        #pragma unroll
        for (int w2 = 1; w2 < 8; ++w2) M = fmaxf(M, m_l[w2][q]);
        float L = 0.f, fac[8];
        #pragma unroll
        for (int w2 = 0; w2 < 8; ++w2) {
            fac[w2] = exp2f((m_l[w2][q] - M) * LOG2E_C);
            L += l_l[w2][q] * fac[w2];
        }
        const float invL = 1.f / L;
        float o0 = 0.f, o1 = 0.f;
        #pragma unroll
        for (int w2 = 0; w2 < 8; ++w2) {
            o0 += o_lds[w2][dp * 2][q] * fac[w2];
            o1 += o_lds[w2][dp * 2 + 1][q] * fac[w2];
        }
        o0 = fmaxf(o0 * invL, 0.f);
        o1 = fmaxf(o1 * invL, 0.f);
        float2 ov = make_float2(o0, o1);
        *reinterpret_cast<float2*>(out + ((size_t)(b * N_ + q0 + q) * H_ + h) * D_ + dp * 2) = ov;
    }
}

extern "C" void kernel_launch(void* const* d_in, const int* in_sizes, int n_in,
                              void* d_out, int out_size, void* d_ws, size_t ws_size,
                              hipStream_t stream) {
    // inputs: vt, x, adj, fc_w, fc_b, Q1, Q2, K, V (all fp32)
    const float* x    = (const float*)d_in[1];
    const float* adj  = (const float*)d_in[2];
    const float* fc_w = (const float*)d_in[3];
    const float* fc_b = (const float*)d_in[4];
    const float* Q1   = (const float*)d_in[5];
    const float* Q2   = (const float*)d_in[6];
    const float* K    = (const float*)d_in[7];
    const float* V    = (const float*)d_in[8];
    float* out = (float*)d_out;

    char* ws = (char*)d_ws;
    const size_t MB = 1024 * 1024;
    unsigned short* QtH = (unsigned short*)(ws);             // 2 MB each
    unsigned short* QtL = (unsigned short*)(ws + 2 * MB);
    unsigned short* KtH = (unsigned short*)(ws + 4 * MB);
    unsigned short* KtL = (unsigned short*)(ws + 6 * MB);
    unsigned short* Vt  = (unsigned short*)(ws + 8 * MB);
    unsigned short* VtT = (unsigned short*)(ws + 10 * MB);
    unsigned*     maskT = (unsigned*)    (ws + 12 * MB);     // 2 MB

    hipLaunchKernelGGL(pack_adjT, dim3(2048), dim3(256), 0, stream, adj, maskT);
    hipLaunchKernelGGL(proj_kernel, dim3(B_ * N_), dim3(128), 0, stream,
                       x, fc_w, fc_b, Q1, Q2, K, V, QtH, QtL, KtH, KtL, Vt);
    hipLaunchKernelGGL(vtrans, dim3(8 * (N_ / 64)), dim3(256), 0, stream, Vt, VtT);
    hipLaunchKernelGGL(flash_mfma, dim3(B_ * H_ * (N_ / 32)), dim3(512), 0, stream,
                       QtH, QtL, KtH, KtL, VtT, maskT, out);
}

// Round 5
// 124.156 us; speedup vs baseline: 5.0088x; 1.1496x over previous
//
#include <hip/hip_runtime.h>
#include <hip/hip_bf16.h>

#define NEG_SLOPE_C 0.1f
#define LOG2E_C 1.4426950408889634f
#define NEGB_C (-1.3e16f)            // -9e15 * log2(e), rounded down (log2-domain mask value)

constexpr int B_ = 2, N_ = 4096, IN_ = 64, H_ = 4, D_ = 32;

typedef float f32x16 __attribute__((ext_vector_type(16)));
typedef __bf16 bf16x8 __attribute__((ext_vector_type(8)));

__device__ inline unsigned short f2bfu(float x) {           // RNE f32 -> bf16 bits
    unsigned u = __float_as_uint(x);
    return (unsigned short)((u + 0x7fffu + ((u >> 16) & 1u)) >> 16);
}
__device__ inline float bfu2f(unsigned short s) { return __uint_as_float(((unsigned)s) << 16); }
__device__ inline bf16x8 ld_bf8(const unsigned short* p) {
    uint4 r = *reinterpret_cast<const uint4*>(p);
    return __builtin_bit_cast(bf16x8, r);
}

// -------- Kernel P: transpose fc_w [128][64] -> fc_wT [64][128] (32 KB, trivial) --------
__global__ __launch_bounds__(256) void prep_fcT(const float* __restrict__ fc_w,
                                                float* __restrict__ fc_wT) {
    int t = blockIdx.x * 256 + threadIdx.x;   // 8192 threads
    int c = t >> 6, k = t & 63;
    fc_wT[k * 128 + c] = fc_w[c * 64 + k];
}

// ---------- Kernel A: adj -> transposed bitmask maskT[qg*N + m], bit q = adj[qg*32+q][m] ----------
__global__ __launch_bounds__(256) void pack_adjT(const float* __restrict__ adj,
                                                 unsigned* __restrict__ maskT) {
    const int g = blockIdx.x * 4 + (threadIdx.x >> 6);   // global wave id, 8192 total
    const int lane = threadIdx.x & 63;
    const int qg = g >> 6;            // 0..127
    const int mc = g & 63;            // 64-key chunk
    const float* ap = adj + (size_t)qg * 32 * N_ + mc * 64 + lane;
    unsigned word = 0;
    #pragma unroll
    for (int i = 0; i < 32; ++i) {
        unsigned long long ball = __ballot(ap[(size_t)i * N_] != 0.0f);
        word |= (unsigned)((ball >> lane) & 1ULL) << i;
    }
    maskT[(size_t)qg * N_ + mc * 64 + lane] = word;
}

// ------------- Kernel B: projections -> bf16 hi/lo splits + V row-major (bf16) -------------
__global__ __launch_bounds__(128) void proj_kernel(
    const float* __restrict__ x, const float* __restrict__ fc_wT,
    const float* __restrict__ fc_b, const float* __restrict__ Q1,
    const float* __restrict__ Q2, const float* __restrict__ K,
    const float* __restrict__ V,
    unsigned short* __restrict__ QtH, unsigned short* __restrict__ QtL,
    unsigned short* __restrict__ KtH, unsigned short* __restrict__ KtL,
    unsigned short* __restrict__ Vt) {
    int bn = blockIdx.x;          // 0..B*N-1
    int b = bn / N_, n = bn % N_;
    int t = threadIdx.x;          // 0..127
    __shared__ float xr[IN_];
    __shared__ float xp[H_ * D_];
    if (t < IN_) xr[t] = x[(long long)bn * IN_ + t];
    __syncthreads();
    float acc = fc_b[t];
    #pragma unroll
    for (int k = 0; k < IN_; ++k) acc += xr[k] * fc_wT[k * 128 + t];  // coalesced, L1-hit
    xp[t] = acc;
    __syncthreads();
    int h = t >> 5, e = t & 31;
    const float* xph = xp + h * D_;
    const float* q1p = Q1 + h * D_ * D_;
    const float* q2p = Q2 + h * D_ * D_;
    const float* kp  = K  + h * D_ * D_;
    const float* vp  = V  + h * D_ * D_;
    float a1 = 0.f, a2 = 0.f, ak = 0.f, av = 0.f;
    #pragma unroll
    for (int d = 0; d < D_; ++d) {
        float xv = xph[d];
        a1 += xv * q1p[d * D_ + e];
        a2 += xv * q2p[d * D_ + e];
        ak += xv * kp [d * D_ + e];
        av += xv * vp [d * D_ + e];
    }
    float q = a1 + a2;
    q = q >= 0.f ? q : NEG_SLOPE_C * q;   // Qt = leaky(Qt1+Qt2)
    size_t o = ((size_t)(b * H_ + h) * N_ + n) * D_ + e;
    unsigned short qh = f2bfu(q);
    QtH[o] = qh;
    QtL[o] = f2bfu(q - bfu2f(qh));
    unsigned short kh = f2bfu(ak);
    KtH[o] = kh;
    KtL[o] = f2bfu(ak - bfu2f(kh));
    Vt[o]  = f2bfu(av);                   // row-major, coalesced
}

// ------------- Kernel B2: Vt [bh][n][d] -> VtT [bh][d][n] (LDS tile transpose) -------------
__global__ __launch_bounds__(256) void vtrans(const unsigned short* __restrict__ Vt,
                                              unsigned short* __restrict__ VtT) {
    const int bh = blockIdx.x >> 6;
    const int n0 = (blockIdx.x & 63) * 64;
    __shared__ unsigned short tile[64][34];
    const int t = threadIdx.x;
    {
        const int r = t >> 2, c = (t & 3) * 8;
        uint4 v = *reinterpret_cast<const uint4*>(Vt + ((size_t)bh * N_ + n0 + r) * D_ + c);
        *reinterpret_cast<uint4*>(&tile[r][c]) = v;
    }
    __syncthreads();
    {
        const int d = t >> 3, nc = (t & 7) * 8;
        unsigned short tmp[8];
        #pragma unroll
        for (int j = 0; j < 8; ++j) tmp[j] = tile[nc + j][d];
        *reinterpret_cast<uint4*>(VtT + ((size_t)bh * D_ + d) * N_ + n0 + nc) =
            *reinterpret_cast<uint4*>(tmp);
    }
}

// ---------------- Kernel C: MFMA flash attention, 32 queries/block, 8-way key split ----------------
__global__ __launch_bounds__(512, 6) void flash_mfma(
    const unsigned short* __restrict__ QtH, const unsigned short* __restrict__ QtL,
    const unsigned short* __restrict__ KtH, const unsigned short* __restrict__ KtL,
    const unsigned short* __restrict__ VtT, const unsigned* __restrict__ maskT,
    float* __restrict__ out) {
    const int bid = blockIdx.x;      // 1024 blocks
    const int bh = bid >> 7;         // 0..7
    const int qg = bid & 127;        // 32-query group
    const int b = bh >> 2, h = bh & 3;
    const int t = threadIdx.x;
    const int w = t >> 6;            // key-split wave 0..7
    const int wu = __builtin_amdgcn_readfirstlane(w);
    const int l = t & 63;
    const int lq = l & 31;           // this lane's query column
    const int hi = l >> 5;
    const int q0 = qg * 32;

    const size_t bhND = (size_t)bh * N_ * D_;
    // Q B-fragments: B[k=dim][col=q]
    const unsigned short* qbh = QtH + bhND + (size_t)(q0 + lq) * D_ + hi * 8;
    const unsigned short* qbl = QtL + bhND + (size_t)(q0 + lq) * D_ + hi * 8;
    const bf16x8 qh0 = ld_bf8(qbh), qh1 = ld_bf8(qbh + 16);
    const bf16x8 ql0 = ld_bf8(qbl), ql1 = ld_bf8(qbl + 16);

    f32x16 acc = {};                 // O^T: row=d, col=q
    float m_run = -3.0e38f, l_run = 0.f;   // m in log2 units
    const float negb = NEGB_C;
    const float C1 = 0.55f * LOG2E_C, C2 = 0.45f * LOG2E_C;

    const int kw0 = wu * 512;
    const unsigned short* kh_p = KtH + bhND + (size_t)(kw0 + lq) * D_ + hi * 8;
    const unsigned short* kl_p = KtL + bhND + (size_t)(kw0 + lq) * D_ + hi * 8;
    const unsigned short* v_p  = VtT + ((size_t)bh * D_ + lq) * N_ + kw0 + hi * 8;
    const unsigned* mp = maskT + (size_t)qg * N_ + wu * 512;   // wave-uniform

    for (int tt = 0; tt < 16; ++tt) {
        // wave-uniform mask words for this 32-key tile
        unsigned mwd[32];
        {
            const uint4* mq = reinterpret_cast<const uint4*>(mp + tt * 32);
            #pragma unroll
            for (int i = 0; i < 8; ++i) {
                uint4 v = mq[i];
                mwd[i*4] = v.x; mwd[i*4+1] = v.y; mwd[i*4+2] = v.z; mwd[i*4+3] = v.w;
            }
        }
        const bf16x8 kh0v = ld_bf8(kh_p), kh1v = ld_bf8(kh_p + 16);
        const bf16x8 kl0v = ld_bf8(kl_p), kl1v = ld_bf8(kl_p + 16);
        const bf16x8 v0   = ld_bf8(v_p),  v1   = ld_bf8(v_p + 16);
        kh_p += 32 * D_; kl_p += 32 * D_; v_p += 32;

        f32x16 s = {};
        s = __builtin_amdgcn_mfma_f32_32x32x16_bf16(kh0v, qh0, s, 0, 0, 0);
        s = __builtin_amdgcn_mfma_f32_32x32x16_bf16(kh1v, qh1, s, 0, 0, 0);
        s = __builtin_amdgcn_mfma_f32_32x32x16_bf16(kh0v, ql0, s, 0, 0, 0);
        s = __builtin_amdgcn_mfma_f32_32x32x16_bf16(kh1v, ql1, s, 0, 0, 0);
        s = __builtin_amdgcn_mfma_f32_32x32x16_bf16(kl0v, qh0, s, 0, 0, 0);
        s = __builtin_amdgcn_mfma_f32_32x32x16_bf16(kl1v, qh1, s, 0, 0, 0);

        // am = log2-scaled leaky score, masked: 2 fma + 1 cndmask per element
        float am[16];
        #pragma unroll
        for (int r = 0; r < 16; ++r) {
            const int j0 = (r & 3) + 8 * (r >> 2);
            const unsigned long long msk =
                (unsigned long long)mwd[j0] | ((unsigned long long)mwd[j0 + 4] << 32);
            const float v = s[r];
            const float a = fmaf(C2, fabsf(v), C1 * v);
            asm("v_cndmask_b32 %0, %1, %2, %3"
                : "=v"(am[r]) : "v"(negb), "v"(a), "s"(msk));
        }
        // row max (max3-friendly trees), cross-half via shfl_xor (proven path)
        const float x0 = fmaxf(fmaxf(am[0], am[1]), am[2]);
        const float x1 = fmaxf(fmaxf(am[3], am[4]), am[5]);
        const float x2 = fmaxf(fmaxf(am[6], am[7]), am[8]);
        const float x3 = fmaxf(fmaxf(am[9], am[10]), am[11]);
        const float x4 = fmaxf(fmaxf(am[12], am[13]), am[14]);
        const float y0 = fmaxf(fmaxf(x0, x1), x2);
        const float y1 = fmaxf(fmaxf(x3, x4), am[15]);
        float cmax = fmaxf(y0, y1);
        cmax = fmaxf(cmax, __shfl_xor(cmax, 32));
        if (!__all(cmax <= m_run)) {
            const float nm = fmaxf(m_run, cmax);
            const float sc = exp2f(m_run - nm);
            l_run *= sc;
            #pragma unroll
            for (int r = 0; r < 16; ++r) acc[r] *= sc;
            m_run = nm;
        }
        float e[16];
        #pragma unroll
        for (int r = 0; r < 16; ++r) e[r] = exp2f(am[r] - m_run);
        const float s0 = (e[0] + e[1]) + (e[2] + e[3]);
        const float s1 = (e[4] + e[5]) + (e[6] + e[7]);
        const float s2 = (e[8] + e[9]) + (e[10] + e[11]);
        const float s3 = (e[12] + e[13]) + (e[14] + e[15]);
        float lsum = (s0 + s1) + (s2 + s3);
        lsum += __shfl_xor(lsum, 32);
        l_run += lsum;
        // P -> bf16 pairs: 8 cvt_pk + 4 permlane32_swap (proven in r3)
        unsigned c0w, c1w, c2w, c3w, c4w, c5w, c6w, c7w;
        asm("v_cvt_pk_bf16_f32 %0, %1, %2" : "=v"(c0w) : "v"(e[0]),  "v"(e[1]));
        asm("v_cvt_pk_bf16_f32 %0, %1, %2" : "=v"(c1w) : "v"(e[2]),  "v"(e[3]));
        asm("v_cvt_pk_bf16_f32 %0, %1, %2" : "=v"(c2w) : "v"(e[4]),  "v"(e[5]));
        asm("v_cvt_pk_bf16_f32 %0, %1, %2" : "=v"(c3w) : "v"(e[6]),  "v"(e[7]));
        asm("v_cvt_pk_bf16_f32 %0, %1, %2" : "=v"(c4w) : "v"(e[8]),  "v"(e[9]));
        asm("v_cvt_pk_bf16_f32 %0, %1, %2" : "=v"(c5w) : "v"(e[10]), "v"(e[11]));
        asm("v_cvt_pk_bf16_f32 %0, %1, %2" : "=v"(c6w) : "v"(e[12]), "v"(e[13]));
        asm("v_cvt_pk_bf16_f32 %0, %1, %2" : "=v"(c7w) : "v"(e[14]), "v"(e[15]));
        asm("v_permlane32_swap_b32 %0, %1" : "+v"(c0w), "+v"(c2w));
        asm("v_permlane32_swap_b32 %0, %1" : "+v"(c1w), "+v"(c3w));
        asm("v_permlane32_swap_b32 %0, %1" : "+v"(c4w), "+v"(c6w));
        asm("v_permlane32_swap_b32 %0, %1" : "+v"(c5w), "+v"(c7w));
        const uint4 b0u = make_uint4(c0w, c1w, c2w, c3w);
        const uint4 b1u = make_uint4(c4w, c5w, c6w, c7w);
        acc = __builtin_amdgcn_mfma_f32_32x32x16_bf16(v0, __builtin_bit_cast(bf16x8, b0u), acc, 0, 0, 0);
        acc = __builtin_amdgcn_mfma_f32_32x32x16_bf16(v1, __builtin_bit_cast(bf16x8, b1u), acc, 0, 0, 0);
    }

    // ---- cross-wave flash merge (8 key-split partials) ----
    __shared__ float o_lds[8][32][33];
    __shared__ float m_l[8][32];
    __shared__ float l_l[8][32];
    if (hi == 0) { m_l[w][lq] = m_run; l_l[w][lq] = l_run; }
    #pragma unroll
    for (int r = 0; r < 16; ++r) {
        const int d = (r & 3) + 8 * (r >> 2) + 4 * hi;
        o_lds[w][d][lq] = acc[r];
    }
    __syncthreads();
    {
        const int q = t >> 4;        // 0..31
        const int dp = t & 15;       // float2 over d
        float M = m_l[0][q];
        #pragma unroll
        for (int w2 = 1; w2 < 8; ++w2) M = fmaxf(M, m_l[w2][q]);
        float L = 0.f, fac[8];
        #pragma unroll
        for (int w2 = 0; w2 < 8; ++w2) {
            fac[w2] = exp2f(m_l[w2][q] - M);
            L += l_l[w2][q] * fac[w2];
        }
        const float invL = 1.f / L;
        float o0 = 0.f, o1 = 0.f;
        #pragma unroll
        for (int w2 = 0; w2 < 8; ++w2) {
            o0 += o_lds[w2][dp * 2][q] * fac[w2];
            o1 += o_lds[w2][dp * 2 + 1][q] * fac[w2];
        }
        o0 = fmaxf(o0 * invL, 0.f);
        o1 = fmaxf(o1 * invL, 0.f);
        float2 ov = make_float2(o0, o1);
        *reinterpret_cast<float2*>(out + ((size_t)(b * N_ + q0 + q) * H_ + h) * D_ + dp * 2) = ov;
    }
}

extern "C" void kernel_launch(void* const* d_in, const int* in_sizes, int n_in,
                              void* d_out, int out_size, void* d_ws, size_t ws_size,
                              hipStream_t stream) {
    // inputs: vt, x, adj, fc_w, fc_b, Q1, Q2, K, V (all fp32)
    const float* x    = (const float*)d_in[1];
    const float* adj  = (const float*)d_in[2];
    const float* fc_w = (const float*)d_in[3];
    const float* fc_b = (const float*)d_in[4];
    const float* Q1   = (const float*)d_in[5];
    const float* Q2   = (const float*)d_in[6];
    const float* K    = (const float*)d_in[7];
    const float* V    = (const float*)d_in[8];
    float* out = (float*)d_out;

    char* ws = (char*)d_ws;
    const size_t MB = 1024 * 1024;
    unsigned short* QtH = (unsigned short*)(ws);             // 2 MB each
    unsigned short* QtL = (unsigned short*)(ws + 2 * MB);
    unsigned short* KtH = (unsigned short*)(ws + 4 * MB);
    unsigned short* KtL = (unsigned short*)(ws + 6 * MB);
    unsigned short* Vt  = (unsigned short*)(ws + 8 * MB);
    unsigned short* VtT = (unsigned short*)(ws + 10 * MB);
    unsigned*     maskT = (unsigned*)    (ws + 12 * MB);     // 2 MB
    float*        fc_wT = (float*)       (ws + 14 * MB);     // 32 KB

    hipLaunchKernelGGL(prep_fcT, dim3(32), dim3(256), 0, stream, fc_w, fc_wT);
    hipLaunchKernelGGL(pack_adjT, dim3(2048), dim3(256), 0, stream, adj, maskT);
    hipLaunchKernelGGL(proj_kernel, dim3(B_ * N_), dim3(128), 0, stream,
                       x, fc_wT, fc_b, Q1, Q2, K, V, QtH, QtL, KtH, KtL, Vt);
    hipLaunchKernelGGL(vtrans, dim3(8 * (N_ / 64)), dim3(256), 0, stream, Vt, VtT);
    hipLaunchKernelGGL(flash_mfma, dim3(B_ * H_ * (N_ / 32)), dim3(512), 0, stream,
                       QtH, QtL, KtH, KtL, VtT, maskT, out);
}

// Round 7
// 105.283 us; speedup vs baseline: 5.9067x; 1.1793x over previous
//
#include <hip/hip_runtime.h>
#include <hip/hip_bf16.h>

#define NEG_SLOPE_C 0.1f
#define LOG2E_C 1.4426950408889634f
#define NEGB_C (-1.3e16f)            // -9e15 * log2(e), rounded down (log2-domain mask value)

constexpr int B_ = 2, N_ = 4096, IN_ = 64, H_ = 4, D_ = 32;

typedef float f32x16 __attribute__((ext_vector_type(16)));
typedef __bf16 bf16x8 __attribute__((ext_vector_type(8)));

__device__ inline unsigned short f2bfu(float x) {           // RNE f32 -> bf16 bits
    unsigned u = __float_as_uint(x);
    return (unsigned short)((u + 0x7fffu + ((u >> 16) & 1u)) >> 16);
}
__device__ inline float bfu2f(unsigned short s) { return __uint_as_float(((unsigned)s) << 16); }
__device__ inline bf16x8 ld_bf8(const unsigned short* p) {
    uint4 r = *reinterpret_cast<const uint4*>(p);
    return __builtin_bit_cast(bf16x8, r);
}

// -------- Kernel P: transpose fc_w [128][64] -> fc_wT [64][128] (32 KB, trivial) --------
__global__ __launch_bounds__(256) void prep_fcT(const float* __restrict__ fc_w,
                                                float* __restrict__ fc_wT) {
    int t = blockIdx.x * 256 + threadIdx.x;   // 8192 threads
    int c = t >> 6, k = t & 63;
    fc_wT[k * 128 + c] = fc_w[c * 64 + k];
}

// ---------- Kernel A: adj -> transposed bitmask maskT[qg*N + m], bit q = adj[qg*32+q][m] ----------
__global__ __launch_bounds__(256) void pack_adjT(const float* __restrict__ adj,
                                                 unsigned* __restrict__ maskT) {
    const int g = blockIdx.x * 4 + (threadIdx.x >> 6);   // global wave id, 8192 total
    const int lane = threadIdx.x & 63;
    const int qg = g >> 6;            // 0..127
    const int mc = g & 63;            // 64-key chunk
    const float* ap = adj + (size_t)qg * 32 * N_ + mc * 64 + lane;
    unsigned word = 0;
    #pragma unroll
    for (int i = 0; i < 32; ++i) {
        unsigned long long ball = __ballot(ap[(size_t)i * N_] != 0.0f);
        word |= (unsigned)((ball >> lane) & 1ULL) << i;
    }
    maskT[(size_t)qg * N_ + mc * 64 + lane] = word;
}

// ------------- Kernel B: projections -> bf16 hi/lo splits + V row-major (bf16) -------------
// 8 rows per block: amortizes block setup, keeps fc_wT hot in L1.
__global__ __launch_bounds__(128) void proj_kernel(
    const float* __restrict__ x, const float* __restrict__ fc_wT,
    const float* __restrict__ fc_b, const float* __restrict__ Q1,
    const float* __restrict__ Q2, const float* __restrict__ K,
    const float* __restrict__ V,
    unsigned short* __restrict__ QtH, unsigned short* __restrict__ QtL,
    unsigned short* __restrict__ KtH, unsigned short* __restrict__ KtL,
    unsigned short* __restrict__ Vt) {
    const int t = threadIdx.x;          // 0..127
    const int h = t >> 5, e = t & 31;
    const float* q1p = Q1 + h * D_ * D_;
    const float* q2p = Q2 + h * D_ * D_;
    const float* kp  = K  + h * D_ * D_;
    const float* vp  = V  + h * D_ * D_;
    __shared__ float xr[IN_];
    __shared__ float xp[H_ * D_];
    const float bias = fc_b[t];
    for (int rr = 0; rr < 8; ++rr) {
        const int bn = blockIdx.x * 8 + rr;   // 0..B*N-1
        const int b = bn / N_, n = bn % N_;
        if (t < IN_) xr[t] = x[(long long)bn * IN_ + t];
        __syncthreads();
        float acc = bias;
        #pragma unroll
        for (int k = 0; k < IN_; ++k) acc += xr[k] * fc_wT[k * 128 + t];  // coalesced, L1-hit
        xp[t] = acc;
        __syncthreads();
        const float* xph = xp + h * D_;
        float a1 = 0.f, a2 = 0.f, ak = 0.f, av = 0.f;
        #pragma unroll
        for (int d = 0; d < D_; ++d) {
            float xv = xph[d];
            a1 += xv * q1p[d * D_ + e];
            a2 += xv * q2p[d * D_ + e];
            ak += xv * kp [d * D_ + e];
            av += xv * vp [d * D_ + e];
        }
        float q = a1 + a2;
        q = q >= 0.f ? q : NEG_SLOPE_C * q;   // Qt = leaky(Qt1+Qt2)
        size_t o = ((size_t)(b * H_ + h) * N_ + n) * D_ + e;
        unsigned short qh = f2bfu(q);
        QtH[o] = qh;
        QtL[o] = f2bfu(q - bfu2f(qh));
        unsigned short kh = f2bfu(ak);
        KtH[o] = kh;
        KtL[o] = f2bfu(ak - bfu2f(kh));
        Vt[o]  = f2bfu(av);                   // row-major, coalesced
        __syncthreads();
    }
}

// ------------- Kernel B2: Vt [bh][n][d] -> VtT [bh][d][n] (LDS tile transpose) -------------
__global__ __launch_bounds__(256) void vtrans(const unsigned short* __restrict__ Vt,
                                              unsigned short* __restrict__ VtT) {
    const int bh = blockIdx.x >> 6;
    const int n0 = (blockIdx.x & 63) * 64;
    __shared__ unsigned short tile[64][34];
    const int t = threadIdx.x;
    {
        const int r = t >> 2, c = (t & 3) * 8;
        uint4 v = *reinterpret_cast<const uint4*>(Vt + ((size_t)bh * N_ + n0 + r) * D_ + c);
        *reinterpret_cast<uint4*>(&tile[r][c]) = v;
    }
    __syncthreads();
    {
        const int d = t >> 3, nc = (t & 7) * 8;
        unsigned short tmp[8];
        #pragma unroll
        for (int j = 0; j < 8; ++j) tmp[j] = tile[nc + j][d];
        *reinterpret_cast<uint4*>(VtT + ((size_t)bh * D_ + d) * N_ + n0 + nc) =
            *reinterpret_cast<uint4*>(tmp);
    }
}

// ---------------- Kernel C: MFMA flash attention, 32 queries/block, 8-way key split ----------------
__global__ __launch_bounds__(512, 6) void flash_mfma(
    const unsigned short* __restrict__ QtH, const unsigned short* __restrict__ QtL,
    const unsigned short* __restrict__ KtH, const unsigned short* __restrict__ KtL,
    const unsigned short* __restrict__ VtT, const unsigned* __restrict__ maskT,
    float* __restrict__ out) {
    const int bid = blockIdx.x;      // 1024 blocks
    const int bh = bid >> 7;         // 0..7
    const int qg = bid & 127;        // 32-query group
    const int b = bh >> 2, h = bh & 3;
    const int t = threadIdx.x;
    const int w = t >> 6;            // key-split wave 0..7
    const int wu = __builtin_amdgcn_readfirstlane(w);
    const int l = t & 63;
    const int lq = l & 31;           // this lane's query column
    const int hi = l >> 5;
    const int q0 = qg * 32;

    const size_t bhND = (size_t)bh * N_ * D_;
    // Q B-fragments: B[k=dim][col=q]
    const unsigned short* qbh = QtH + bhND + (size_t)(q0 + lq) * D_ + hi * 8;
    const unsigned short* qbl = QtL + bhND + (size_t)(q0 + lq) * D_ + hi * 8;
    const bf16x8 qh0 = ld_bf8(qbh), qh1 = ld_bf8(qbh + 16);
    const bf16x8 ql0 = ld_bf8(qbl), ql1 = ld_bf8(qbl + 16);

    f32x16 acc = {};                 // O^T: row=d, col=q
    float m_run = -3.0e38f, l_run = 0.f;   // m in log2 units
    const float negb = NEGB_C;
    const float C1 = 0.55f * LOG2E_C, C2 = 0.45f * LOG2E_C;

    const int kw0 = wu * 512;
    const unsigned short* kh_p = KtH + bhND + (size_t)(kw0 + lq) * D_ + hi * 8;
    const unsigned short* kl_p = KtL + bhND + (size_t)(kw0 + lq) * D_ + hi * 8;
    const unsigned short* v_p  = VtT + ((size_t)bh * D_ + lq) * N_ + kw0 + hi * 8;
    const unsigned* mp = maskT + (size_t)qg * N_ + wu * 512;   // wave-uniform

    for (int tt = 0; tt < 16; ++tt) {
        // wave-uniform mask words for this 32-key tile
        unsigned mwd[32];
        {
            const uint4* mq = reinterpret_cast<const uint4*>(mp + tt * 32);
            #pragma unroll
            for (int i = 0; i < 8; ++i) {
                uint4 v = mq[i];
                mwd[i*4] = v.x; mwd[i*4+1] = v.y; mwd[i*4+2] = v.z; mwd[i*4+3] = v.w;
            }
        }
        const bf16x8 kh0v = ld_bf8(kh_p), kh1v = ld_bf8(kh_p + 16);
        const bf16x8 kl0v = ld_bf8(kl_p), kl1v = ld_bf8(kl_p + 16);
        const bf16x8 v0   = ld_bf8(v_p),  v1   = ld_bf8(v_p + 16);
        kh_p += 32 * D_; kl_p += 32 * D_; v_p += 32;

        f32x16 s = {};
        s = __builtin_amdgcn_mfma_f32_32x32x16_bf16(kh0v, qh0, s, 0, 0, 0);
        s = __builtin_amdgcn_mfma_f32_32x32x16_bf16(kh1v, qh1, s, 0, 0, 0);
        s = __builtin_amdgcn_mfma_f32_32x32x16_bf16(kh0v, ql0, s, 0, 0, 0);
        s = __builtin_amdgcn_mfma_f32_32x32x16_bf16(kh1v, ql1, s, 0, 0, 0);
        s = __builtin_amdgcn_mfma_f32_32x32x16_bf16(kl0v, qh0, s, 0, 0, 0);
        s = __builtin_amdgcn_mfma_f32_32x32x16_bf16(kl1v, qh1, s, 0, 0, 0);

        // am = log2-scaled leaky score, masked: 2 fma + 1 cndmask per element
        float am[16];
        #pragma unroll
        for (int r = 0; r < 16; ++r) {
            const int j0 = (r & 3) + 8 * (r >> 2);
            const unsigned long long msk =
                (unsigned long long)mwd[j0] | ((unsigned long long)mwd[j0 + 4] << 32);
            const float v = s[r];
            const float a = fmaf(C2, fabsf(v), C1 * v);
            asm("v_cndmask_b32 %0, %1, %2, %3"
                : "=v"(am[r]) : "v"(negb), "v"(a), "s"(msk));
        }
        // row max (max3-friendly trees), cross-half via shfl_xor (r5-proven path)
        const float x0 = fmaxf(fmaxf(am[0], am[1]), am[2]);
        const float x1 = fmaxf(fmaxf(am[3], am[4]), am[5]);
        const float x2 = fmaxf(fmaxf(am[6], am[7]), am[8]);
        const float x3 = fmaxf(fmaxf(am[9], am[10]), am[11]);
        const float x4 = fmaxf(fmaxf(am[12], am[13]), am[14]);
        const float y0 = fmaxf(fmaxf(x0, x1), x2);
        const float y1 = fmaxf(fmaxf(x3, x4), am[15]);
        float cmax = fmaxf(y0, y1);
        cmax = fmaxf(cmax, __shfl_xor(cmax, 32));
        if (!__all(cmax <= m_run)) {
            const float nm = fmaxf(m_run, cmax);
            const float sc = __builtin_amdgcn_exp2f(m_run - nm);
            l_run *= sc;
            #pragma unroll
            for (int r = 0; r < 16; ++r) acc[r] *= sc;
            m_run = nm;
        }
        float e[16];
        #pragma unroll
        for (int r = 0; r < 16; ++r) e[r] = __builtin_amdgcn_exp2f(am[r] - m_run);
        const float s0 = (e[0] + e[1]) + (e[2] + e[3]);
        const float s1 = (e[4] + e[5]) + (e[6] + e[7]);
        const float s2 = (e[8] + e[9]) + (e[10] + e[11]);
        const float s3 = (e[12] + e[13]) + (e[14] + e[15]);
        float lsum = (s0 + s1) + (s2 + s3);
        lsum += __shfl_xor(lsum, 32);
        l_run += lsum;
        // P -> bf16 pairs: 8 cvt_pk + 4 permlane32_swap (distinct operands -> safe; r3/r5-proven)
        unsigned c0w, c1w, c2w, c3w, c4w, c5w, c6w, c7w;
        asm("v_cvt_pk_bf16_f32 %0, %1, %2" : "=v"(c0w) : "v"(e[0]),  "v"(e[1]));
        asm("v_cvt_pk_bf16_f32 %0, %1, %2" : "=v"(c1w) : "v"(e[2]),  "v"(e[3]));
        asm("v_cvt_pk_bf16_f32 %0, %1, %2" : "=v"(c2w) : "v"(e[4]),  "v"(e[5]));
        asm("v_cvt_pk_bf16_f32 %0, %1, %2" : "=v"(c3w) : "v"(e[6]),  "v"(e[7]));
        asm("v_cvt_pk_bf16_f32 %0, %1, %2" : "=v"(c4w) : "v"(e[8]),  "v"(e[9]));
        asm("v_cvt_pk_bf16_f32 %0, %1, %2" : "=v"(c5w) : "v"(e[10]), "v"(e[11]));
        asm("v_cvt_pk_bf16_f32 %0, %1, %2" : "=v"(c6w) : "v"(e[12]), "v"(e[13]));
        asm("v_cvt_pk_bf16_f32 %0, %1, %2" : "=v"(c7w) : "v"(e[14]), "v"(e[15]));
        asm("v_permlane32_swap_b32 %0, %1" : "+v"(c0w), "+v"(c2w));
        asm("v_permlane32_swap_b32 %0, %1" : "+v"(c1w), "+v"(c3w));
        asm("v_permlane32_swap_b32 %0, %1" : "+v"(c4w), "+v"(c6w));
        asm("v_permlane32_swap_b32 %0, %1" : "+v"(c5w), "+v"(c7w));
        const uint4 b0u = make_uint4(c0w, c1w, c2w, c3w);
        const uint4 b1u = make_uint4(c4w, c5w, c6w, c7w);
        acc = __builtin_amdgcn_mfma_f32_32x32x16_bf16(v0, __builtin_bit_cast(bf16x8, b0u), acc, 0, 0, 0);
        acc = __builtin_amdgcn_mfma_f32_32x32x16_bf16(v1, __builtin_bit_cast(bf16x8, b1u), acc, 0, 0, 0);
    }

    // ---- cross-wave flash merge (8 key-split partials) ----
    __shared__ float o_lds[8][32][33];
    __shared__ float m_l[8][32];
    __shared__ float l_l[8][32];
    if (hi == 0) { m_l[w][lq] = m_run; l_l[w][lq] = l_run; }
    #pragma unroll
    for (int r = 0; r < 16; ++r) {
        const int d = (r & 3) + 8 * (r >> 2) + 4 * hi;
        o_lds[w][d][lq] = acc[r];
    }
    __syncthreads();
    {
        const int q = t >> 4;        // 0..31
        const int dp = t & 15;       // float2 over d
        float M = m_l[0][q];
        #pragma unroll
        for (int w2 = 1; w2 < 8; ++w2) M = fmaxf(M, m_l[w2][q]);
        float L = 0.f, fac[8];
        #pragma unroll
        for (int w2 = 0; w2 < 8; ++w2) {
            fac[w2] = __builtin_amdgcn_exp2f(m_l[w2][q] - M);
            L += l_l[w2][q] * fac[w2];
        }
        const float invL = 1.f / L;
        float o0 = 0.f, o1 = 0.f;
        #pragma unroll
        for (int w2 = 0; w2 < 8; ++w2) {
            o0 += o_lds[w2][dp * 2][q] * fac[w2];
            o1 += o_lds[w2][dp * 2 + 1][q] * fac[w2];
        }
        o0 = fmaxf(o0 * invL, 0.f);
        o1 = fmaxf(o1 * invL, 0.f);
        float2 ov = make_float2(o0, o1);
        *reinterpret_cast<float2*>(out + ((size_t)(b * N_ + q0 + q) * H_ + h) * D_ + dp * 2) = ov;
    }
}

extern "C" void kernel_launch(void* const* d_in, const int* in_sizes, int n_in,
                              void* d_out, int out_size, void* d_ws, size_t ws_size,
                              hipStream_t stream) {
    // inputs: vt, x, adj, fc_w, fc_b, Q1, Q2, K, V (all fp32)
    const float* x    = (const float*)d_in[1];
    const float* adj  = (const float*)d_in[2];
    const float* fc_w = (const float*)d_in[3];
    const float* fc_b = (const float*)d_in[4];
    const float* Q1   = (const float*)d_in[5];
    const float* Q2   = (const float*)d_in[6];
    const float* K    = (const float*)d_in[7];
    const float* V    = (const float*)d_in[8];
    float* out = (float*)d_out;

    char* ws = (char*)d_ws;
    const size_t MB = 1024 * 1024;
    unsigned short* QtH = (unsigned short*)(ws);             // 2 MB each
    unsigned short* QtL = (unsigned short*)(ws + 2 * MB);
    unsigned short* KtH = (unsigned short*)(ws + 4 * MB);
    unsigned short* KtL = (unsigned short*)(ws + 6 * MB);
    unsigned short* Vt  = (unsigned short*)(ws + 8 * MB);
    unsigned short* VtT = (unsigned short*)(ws + 10 * MB);
    unsigned*     maskT = (unsigned*)    (ws + 12 * MB);     // 2 MB
    float*        fc_wT = (float*)       (ws + 14 * MB);     // 32 KB

    hipLaunchKernelGGL(prep_fcT, dim3(32), dim3(256), 0, stream, fc_w, fc_wT);
    hipLaunchKernelGGL(pack_adjT, dim3(2048), dim3(256), 0, stream, adj, maskT);
    hipLaunchKernelGGL(proj_kernel, dim3(B_ * N_ / 8), dim3(128), 0, stream,
                       x, fc_wT, fc_b, Q1, Q2, K, V, QtH, QtL, KtH, KtL, Vt);
    hipLaunchKernelGGL(vtrans, dim3(8 * (N_ / 64)), dim3(256), 0, stream, Vt, VtT);
    hipLaunchKernelGGL(flash_mfma, dim3(B_ * H_ * (N_ / 32)), dim3(512), 0, stream,
                       QtH, QtL, KtH, KtL, VtT, maskT, out);
}